// Round 1
// baseline (138.193 us; speedup 1.0000x reference)
//
#include <hip/hip_runtime.h>
#include <stdint.h>

// DenseAttention_61598420959334 — algebraically restructured:
//   G = x^T x, s = x^T 1                      (pass 1, hi/lo bf16 MFMA)
//   T1 = G Wk^T ; scores = (Wq T1 + rank-1)/sqrt(D) ; W = softmax(scores)
//   M = W Wv ; c = W bv ; wsum = rowsum(Wo)   (small fp32 kernels)
//   per group p (128 rows): U = X_p M^T ; Out_p = (Wo U)^T + c wsum^T + 1 bo^T
// All LDS tiles use matched XOR write/read swizzles (involution => exact content).

#define DD 128
#define ROWS_PER_BLK 1024
#define KSTEPS 32
#define PART_STRIDE 16512  // 16384 G-partial + 128 s-partial

typedef float f32x4 __attribute__((ext_vector_type(4)));
typedef short s16x8 __attribute__((ext_vector_type(8)));
typedef float fvec4 __attribute__((ext_vector_type(4)));

__device__ __forceinline__ unsigned short f2bf(float f) {
    union { float f; uint32_t u; } v; v.f = f;
    uint32_t u = v.u;
    u += 0x7FFFu + ((u >> 16) & 1u);
    return (unsigned short)(u >> 16);
}
__device__ __forceinline__ float bf2f(unsigned short h) {
    union { uint32_t u; float f; } v; v.u = ((uint32_t)h) << 16;
    return v.f;
}

// ---------------------------------------------------------------- pass 1: Gram
__global__ __launch_bounds__(512) void k_gram(const float* __restrict__ x,
                                              float* __restrict__ ws) {
    __shared__ short xs[2][2][4096];  // [buf][hi/lo][ j*128 + (d ^ ((j&7)<<3)) ]  row-major x tile
    __shared__ short xt[2][2][4096];  // [buf][hi/lo][ a*32  + (j ^ (((a>>1)&3)<<3)) ] transposed tile

    const int tid = threadIdx.x;
    const int l = tid & 63, w = tid >> 6;
    const int hi = l >> 4, c = l & 15;
    const int wr = w >> 1, wc = w & 1;
    const long rowbase = (long)blockIdx.x * ROWS_PER_BLK;
    const fvec4* xg = (const fvec4*)x;

    // constant fragments
    s16x8 ones;
#pragma unroll
    for (int i = 0; i < 8; ++i) ones[i] = (short)0x3F80;
    s16x8 idfw;  // identity B-frag for this wave's a-subtile (at = w, h = w&1)
    {
        int tgt = (w & 1) * 16 + c - hi * 8;
#pragma unroll
        for (int i = 0; i < 8; ++i) idfw[i] = (i == tgt) ? (short)0x3F80 : (short)0;
    }

    f32x4 acc[2][4] = {};  // G tiles (ma = wr*2+mi, nb = wc*4+ni)
    f32x4 accs = {};       // colsum tile (nb = wc*4+wr)
    const f32x4 zero4 = {};

    fvec4 rA0, rA1, rB0, rB1;

#define LOADS(kt, r0, r1) do {                                  \
        long _b = (rowbase + (long)(kt) * 32) * 32;             \
        r0 = xg[_b + tid]; r1 = xg[_b + 512 + tid];             \
    } while (0)

#define CVTWRITE(BUF, r0, r1) do {                                              \
        _Pragma("unroll")                                                       \
        for (int _q = 0; _q < 2; ++_q) {                                        \
            fvec4 _v = _q ? r1 : r0;                                            \
            int _ft = tid + _q * 512;                                           \
            int _j = _ft >> 5, _d0 = (_ft & 31) * 4;                            \
            uint64_t _ph = 0, _pl = 0;                                          \
            _Pragma("unroll")                                                   \
            for (int _e = 0; _e < 4; ++_e) {                                    \
                float _f = _v[_e];                                              \
                unsigned short _hb = f2bf(_f);                                  \
                unsigned short _lb = f2bf(_f - bf2f(_hb));                      \
                _ph |= (uint64_t)_hb << (16 * _e);                              \
                _pl |= (uint64_t)_lb << (16 * _e);                              \
            }                                                                   \
            int _idx = _j * 128 + (_d0 ^ ((_j & 7) << 3));                      \
            *(uint64_t*)&xs[BUF][0][_idx] = _ph;                                \
            *(uint64_t*)&xs[BUF][1][_idx] = _pl;                                \
        }                                                                       \
    } while (0)

    // transpose tile into xt via identity MFMA: D[j_loc][a_loc] = x[j][a]
#define XTBUILD(BUF) do {                                                       \
        const int _ks = w >> 1;                                                 \
        _Pragma("unroll")                                                       \
        for (int _jt = 0; _jt < 2; ++_jt) {                                     \
            int _j = _jt * 16 + c;                                              \
            int _rb = _j * 128 + ((_ks * 32 + hi * 8) ^ ((_j & 7) << 3));       \
            _Pragma("unroll")                                                   \
            for (int _hl = 0; _hl < 2; ++_hl) {                                 \
                s16x8 _af = *(const s16x8*)&xs[BUF][_hl][_rb];                  \
                f32x4 _d = __builtin_amdgcn_mfma_f32_16x16x32_bf16(_af, idfw, zero4, 0, 0, 0); \
                int _a = w * 16 + c;                                            \
                int _j0 = _jt * 16 + hi * 4;                                    \
                uint64_t _pk = 0;                                               \
                _Pragma("unroll")                                               \
                for (int _e = 0; _e < 4; ++_e) _pk |= (uint64_t)f2bf(_d[_e]) << (16 * _e); \
                *(uint64_t*)&xt[BUF][_hl][_a * 32 + (_j0 ^ (((_a >> 1) & 3) << 3))] = _pk; \
            }                                                                   \
        }                                                                       \
    } while (0)

#define GRAM(BUF) do {                                                          \
        s16x8 Ah[2], Al[2], Bh[4], Bl[4];                                       \
        _Pragma("unroll")                                                       \
        for (int _mi = 0; _mi < 2; ++_mi) {                                     \
            int _a = (wr * 2 + _mi) * 16 + c;                                   \
            int _idx = _a * 32 + ((hi * 8) ^ (((_a >> 1) & 3) << 3));           \
            Ah[_mi] = *(const s16x8*)&xt[BUF][0][_idx];                         \
            Al[_mi] = *(const s16x8*)&xt[BUF][1][_idx];                         \
        }                                                                       \
        _Pragma("unroll")                                                       \
        for (int _ni = 0; _ni < 4; ++_ni) {                                     \
            int _b = (wc * 4 + _ni) * 16 + c;                                   \
            int _idx = _b * 32 + ((hi * 8) ^ (((_b >> 1) & 3) << 3));           \
            Bh[_ni] = *(const s16x8*)&xt[BUF][0][_idx];                         \
            Bl[_ni] = *(const s16x8*)&xt[BUF][1][_idx];                         \
        }                                                                       \
        _Pragma("unroll")                                                       \
        for (int _mi = 0; _mi < 2; ++_mi) {                                     \
            _Pragma("unroll")                                                   \
            for (int _ni = 0; _ni < 4; ++_ni) {                                 \
                acc[_mi][_ni] = __builtin_amdgcn_mfma_f32_16x16x32_bf16(Ah[_mi], Bh[_ni], acc[_mi][_ni], 0, 0, 0); \
                acc[_mi][_ni] = __builtin_amdgcn_mfma_f32_16x16x32_bf16(Ah[_mi], Bl[_ni], acc[_mi][_ni], 0, 0, 0); \
                acc[_mi][_ni] = __builtin_amdgcn_mfma_f32_16x16x32_bf16(Al[_mi], Bh[_ni], acc[_mi][_ni], 0, 0, 0); \
                if (_ni == wr) {                                                \
                    accs = __builtin_amdgcn_mfma_f32_16x16x32_bf16(ones, Bh[_ni], accs, 0, 0, 0); \
                    accs = __builtin_amdgcn_mfma_f32_16x16x32_bf16(ones, Bl[_ni], accs, 0, 0, 0); \
                }                                                               \
            }                                                                   \
        }                                                                       \
    } while (0)

    // prologue
    LOADS(0, rA0, rA1);
    CVTWRITE(0, rA0, rA1);
    LOADS(1, rB0, rB1);
    __syncthreads();

    for (int kt = 0; kt < KSTEPS; kt += 2) {
        if (kt + 2 < KSTEPS) LOADS(kt + 2, rA0, rA1);
        XTBUILD(0);
        __syncthreads();
        GRAM(0);
        if (kt + 1 < KSTEPS) CVTWRITE(1, rB0, rB1);
        __syncthreads();

        if (kt + 3 < KSTEPS) LOADS(kt + 3, rB0, rB1);
        XTBUILD(1);
        __syncthreads();
        GRAM(1);
        if (kt + 2 < KSTEPS) CVTWRITE(0, rA0, rA1);
        __syncthreads();
    }

    // dump partials
    long pbase = (long)blockIdx.x * PART_STRIDE;
#pragma unroll
    for (int mi = 0; mi < 2; ++mi)
#pragma unroll
        for (int ni = 0; ni < 4; ++ni)
#pragma unroll
            for (int e = 0; e < 4; ++e) {
                int a = (wr * 2 + mi) * 16 + hi * 4 + e;
                int b = (wc * 4 + ni) * 16 + c;
                ws[pbase + a * 128 + b] = acc[mi][ni][e];
            }
    if (hi == 0) {
        int nbs = wc * 4 + wr;
        ws[pbase + 16384 + nbs * 16 + c] = accs[0];
    }
#undef LOADS
#undef CVTWRITE
#undef XTBUILD
#undef GRAM
}

// ------------------------------------------------------- reduce partials -> G, s
__global__ __launch_bounds__(256) void k_reduce(const float* __restrict__ parts,
                                                float* __restrict__ g_out,
                                                float* __restrict__ s_out, int nb1) {
    __shared__ float red[256];
    int b = blockIdx.x, t = threadIdx.x;
    if (b < 512) {
        int d1 = b >> 2, q = b & 3;
        int c32 = t & 31, pg = t >> 5;
        int per = nb1 >> 3;
        int e = d1 * 128 + q * 32 + c32;
        float acc = 0.f;
#pragma unroll 4
        for (int p = pg * per; p < (pg + 1) * per; ++p)
            acc += parts[(long)p * PART_STRIDE + e];
        red[t] = acc;
        __syncthreads();
        if (pg == 0) {
            float s = red[c32];
#pragma unroll
            for (int k = 1; k < 8; ++k) s += red[k * 32 + c32];
            g_out[e] = s;
        }
    } else {
        int ee = t & 127, hg = t >> 7;
        int per = nb1 >> 1;
        float acc = 0.f;
#pragma unroll 4
        for (int p = hg * per; p < (hg + 1) * per; ++p)
            acc += parts[(long)p * PART_STRIDE + 16384 + ee];
        red[t] = acc;
        __syncthreads();
        if (hg == 0) s_out[ee] = red[ee] + red[128 + ee];
    }
}

// ------------------------------------------------------------- T1 = G Wk^T (fp32)
__global__ __launch_bounds__(256) void k_t1(const float* __restrict__ G,
                                            const float* __restrict__ Wk,
                                            const float* __restrict__ s,
                                            float* __restrict__ T1,
                                            float* __restrict__ ksv) {
    __shared__ float wk[128 * 129];
    __shared__ float grow[128];
    __shared__ float sl[128];
    int t = threadIdx.x, d1 = blockIdx.x;
    for (int idx = t; idx < 16384; idx += 256) {
        int r = idx >> 7, cc = idx & 127;
        wk[r * 129 + cc] = Wk[idx];
    }
    if (t < 128) { grow[t] = G[d1 * 128 + t]; sl[t] = s[t]; }
    __syncthreads();
    if (t < 128) {
        float acc = 0.f;
#pragma unroll 4
        for (int d2 = 0; d2 < 128; ++d2) acc += grow[d2] * wk[t * 129 + d2];
        T1[d1 * 128 + t] = acc;
        if (d1 == 0) {
            float a2 = 0.f;
#pragma unroll 4
            for (int d2 = 0; d2 < 128; ++d2) a2 += sl[d2] * wk[t * 129 + d2];
            ksv[t] = a2;
        }
    }
}

// --------------------------------------------------- scores row + softmax (fp32)
__global__ __launch_bounds__(128) void k_scores(const float* __restrict__ T1,
                                                const float* __restrict__ Wq,
                                                const float* __restrict__ bq,
                                                const float* __restrict__ bk,
                                                const float* __restrict__ s,
                                                const float* __restrict__ ksv,
                                                float* __restrict__ Wout, float Bn) {
    __shared__ float t1l[16384];
    __shared__ float wqr[128], sl[128], ksl[128], bkl[128], scl[128];
    int t = threadIdx.x, a = blockIdx.x;
    for (int idx = t; idx < 16384; idx += 128) t1l[idx] = T1[idx];
    wqr[t] = Wq[a * 128 + t];
    sl[t] = s[t]; ksl[t] = ksv[t]; bkl[t] = bk[t];
    __syncthreads();
    float sc = 0.f;
#pragma unroll 4
    for (int d1 = 0; d1 < 128; ++d1) sc += wqr[d1] * t1l[d1 * 128 + t];
    float qs = 0.f;
#pragma unroll 4
    for (int d = 0; d < 128; ++d) qs += wqr[d] * sl[d];
    float bqa = bq[a];
    sc = (sc + qs * bkl[t] + bqa * ksl[t] + Bn * bqa * bkl[t]) * 0.0883883476483184406f;
    scl[t] = sc;
    __syncthreads();
    float mx = -1e30f;
    for (int i2 = 0; i2 < 128; ++i2) mx = fmaxf(mx, scl[i2]);
    float e = expf(sc - mx);
    __syncthreads();
    scl[t] = e;
    __syncthreads();
    float sum = 0.f;
    for (int i2 = 0; i2 < 128; ++i2) sum += scl[i2];
    Wout[a * 128 + t] = e / sum;
}

// ---------------------------------- M = W Wv (bf16 out), c = W bv, Wo cast, wsum
__global__ __launch_bounds__(256) void k_m(const float* __restrict__ Wmat,
                                           const float* __restrict__ Wv,
                                           const float* __restrict__ bv,
                                           const float* __restrict__ Wo,
                                           unsigned short* __restrict__ M16,
                                           unsigned short* __restrict__ Wo16,
                                           float* __restrict__ cvec,
                                           float* __restrict__ wsum) {
    __shared__ float wrow[128], bvl[128], worow[128];
    __shared__ float part[2][128];
    int t = threadIdx.x, a = blockIdx.x;
    if (t < 128) { wrow[t] = Wmat[a * 128 + t]; bvl[t] = bv[t]; worow[t] = Wo[a * 128 + t]; }
    __syncthreads();
    int dd = t & 127, ch = t >> 7;
    float macc = 0.f;
#pragma unroll 4
    for (int cc = ch * 64; cc < ch * 64 + 64; ++cc)
        macc += wrow[cc] * Wv[cc * 128 + dd];
    part[ch][dd] = macc;
    __syncthreads();
    if (t < 128) {
        M16[a * 128 + t] = f2bf(part[0][t] + part[1][t]);
        Wo16[a * 128 + t] = f2bf(worow[t]);
    }
    if (t == 0) {
        float cv = 0.f, wsm = 0.f;
        for (int cc = 0; cc < 128; ++cc) { cv += wrow[cc] * bvl[cc]; wsm += worow[cc]; }
        cvec[a] = cv; wsum[a] = wsm;
    }
}

// ------------------------------- pass 2: per-group double GEMM -> output rows
__global__ __launch_bounds__(256) void k_out(const float* __restrict__ x,
                                             const unsigned short* __restrict__ M16,
                                             const unsigned short* __restrict__ Wo16,
                                             const float* __restrict__ cvec,
                                             const float* __restrict__ wsum,
                                             const float* __restrict__ bo,
                                             float* __restrict__ out, int ngrp) {
    __shared__ short xsk[16384];  // [j][d] bf16, swizzled
    __shared__ short ut[16384];   // [r][j] bf16 = U^T, swizzled
    __shared__ float csl[128], wsl[128], bol[128];
    int t = threadIdx.x;
    int l = t & 63, w = t >> 6, hi = l >> 4, c = l & 15;
    int p = blockIdx.x;

    // B-fragments from global (L2-resident), issued early
    s16x8 bfM[2][4], bfO[2][4];
#pragma unroll
    for (int rt = 0; rt < 2; ++rt) {
        int r = (2 * w + rt) * 16 + c;
#pragma unroll
        for (int ks = 0; ks < 4; ++ks)
            bfM[rt][ks] = *(const s16x8*)&M16[r * 128 + ks * 32 + hi * 8];
    }
#pragma unroll
    for (int ot = 0; ot < 2; ++ot) {
        int o = (2 * w + ot) * 16 + c;
#pragma unroll
        for (int ks = 0; ks < 4; ++ks)
            bfO[ot][ks] = *(const s16x8*)&Wo16[o * 128 + ks * 32 + hi * 8];
    }
    if (t < 128) { csl[t] = cvec[t]; wsl[t] = wsum[t]; bol[t] = bo[t]; }

    // stage X_p as bf16 (coalesced float4 reads)
    const fvec4* xg = (const fvec4*)x;
    long xbase = (long)p * 4096;
#pragma unroll
    for (int kk = 0; kk < 16; ++kk) {
        fvec4 v = xg[xbase + kk * 256 + t];
        int ft = kk * 256 + t;
        int j = ft >> 5, d0 = (ft & 31) * 4;
        uint64_t pk = 0;
#pragma unroll
        for (int e = 0; e < 4; ++e) pk |= (uint64_t)f2bf(v[e]) << (16 * e);
        *(uint64_t*)&xsk[j * 128 + (d0 ^ ((j & 7) << 3))] = pk;
    }
    __syncthreads();

    // GEMM1: U[j][r] = sum_d X[j,d] M[r,d]
    f32x4 acc[8][2] = {};
#pragma unroll
    for (int jt = 0; jt < 8; ++jt) {
        int j = jt * 16 + c;
        s16x8 af[4];
#pragma unroll
        for (int ks = 0; ks < 4; ++ks)
            af[ks] = *(const s16x8*)&xsk[j * 128 + ((ks * 32 + hi * 8) ^ ((j & 7) << 3))];
#pragma unroll
        for (int rt = 0; rt < 2; ++rt)
#pragma unroll
            for (int ks = 0; ks < 4; ++ks)
                acc[jt][rt] = __builtin_amdgcn_mfma_f32_16x16x32_bf16(af[ks], bfM[rt][ks], acc[jt][rt], 0, 0, 0);
    }
    // write U^T to LDS
#pragma unroll
    for (int jt = 0; jt < 8; ++jt)
#pragma unroll
        for (int rt = 0; rt < 2; ++rt) {
            int r = (2 * w + rt) * 16 + c;
            int j0 = jt * 16 + hi * 4;
            uint64_t pk = 0;
#pragma unroll
            for (int e = 0; e < 4; ++e) pk |= (uint64_t)f2bf(acc[jt][rt][e]) << (16 * e);
            *(uint64_t*)&ut[r * 128 + (j0 ^ ((r & 7) << 3))] = pk;
        }
    __syncthreads();

    // GEMM2: Out[r][o] = sum_j U^T[r,j] Wo[o,j]
    f32x4 acc2[8][2] = {};
#pragma unroll
    for (int rt8 = 0; rt8 < 8; ++rt8) {
        int r = rt8 * 16 + c;
        s16x8 af[4];
#pragma unroll
        for (int ks = 0; ks < 4; ++ks)
            af[ks] = *(const s16x8*)&ut[r * 128 + ((ks * 32 + hi * 8) ^ ((r & 7) << 3))];
#pragma unroll
        for (int ot = 0; ot < 2; ++ot)
#pragma unroll
            for (int ks = 0; ks < 4; ++ks)
                acc2[rt8][ot] = __builtin_amdgcn_mfma_f32_16x16x32_bf16(af[ks], bfO[ot][ks], acc2[rt8][ot], 0, 0, 0);
    }
    // epilogue: out[(r*ngrp + p)*128 + o] = acc + c[r]*wsum[o] + bo[o]
#pragma unroll
    for (int rt8 = 0; rt8 < 8; ++rt8)
#pragma unroll
        for (int ot = 0; ot < 2; ++ot)
#pragma unroll
            for (int e = 0; e < 4; ++e) {
                int r = rt8 * 16 + hi * 4 + e;
                int o = (2 * w + ot) * 16 + c;
                float val = acc2[rt8][ot][e] + csl[r] * wsl[o] + bol[o];
                out[((long)r * ngrp + p) * 128 + o] = val;
            }
}

// ------------------------------------------------------------------- launcher
extern "C" void kernel_launch(void* const* d_in, const int* in_sizes, int n_in,
                              void* d_out, int out_size, void* d_ws, size_t ws_size,
                              hipStream_t stream) {
    const float* x  = (const float*)d_in[0];
    const float* Wq = (const float*)d_in[1];
    const float* bq = (const float*)d_in[2];
    const float* Wk = (const float*)d_in[3];
    const float* bk = (const float*)d_in[4];
    const float* Wv = (const float*)d_in[5];
    const float* bv = (const float*)d_in[6];
    const float* Wo = (const float*)d_in[7];
    const float* bo = (const float*)d_in[8];
    float* out = (float*)d_out;
    float* ws = (float*)d_ws;

    int Bn  = in_sizes[0] / DD;      // 262144
    int nb1 = Bn / ROWS_PER_BLK;     // 256
    int ngrp = Bn / DD;              // 2048

    size_t offG   = (size_t)nb1 * PART_STRIDE;
    size_t offS   = offG + 16384;
    size_t offT1  = offS + 128;
    size_t offKS  = offT1 + 16384;
    size_t offW   = offKS + 128;
    size_t offCV  = offW + 16384;
    size_t offWS  = offCV + 128;
    size_t offM16 = offWS + 128;     // bf16 area (float-indexed)
    size_t offWO16 = offM16 + 8192;

    hipLaunchKernelGGL(k_gram, dim3(nb1), dim3(512), 0, stream, x, ws);
    hipLaunchKernelGGL(k_reduce, dim3(513), dim3(256), 0, stream,
                       ws, ws + offG, ws + offS, nb1);
    hipLaunchKernelGGL(k_t1, dim3(128), dim3(256), 0, stream,
                       ws + offG, Wk, ws + offS, ws + offT1, ws + offKS);
    hipLaunchKernelGGL(k_scores, dim3(128), dim3(128), 0, stream,
                       ws + offT1, Wq, bq, bk, ws + offS, ws + offKS, ws + offW, (float)Bn);
    hipLaunchKernelGGL(k_m, dim3(128), dim3(256), 0, stream,
                       ws + offW, Wv, bv, Wo,
                       (unsigned short*)(ws + offM16), (unsigned short*)(ws + offWO16),
                       ws + offCV, ws + offWS);
    hipLaunchKernelGGL(k_out, dim3(ngrp), dim3(256), 0, stream,
                       x, (const unsigned short*)(ws + offM16), (const unsigned short*)(ws + offWO16),
                       ws + offCV, ws + offWS, bo, out, ngrp);
}